// Round 1
// baseline (1379.820 us; speedup 1.0000x reference)
//
#include <hip/hip_runtime.h>
#include <cstdint>

#define NTOK 49
#define HEADS 16
#define HD 32
#define CDIM 512
#define BW 2048
#define MROWS (BW * NTOK)   // 100352
#define QKVN 1536

typedef __attribute__((ext_vector_type(4))) float f32x4;
typedef __attribute__((ext_vector_type(8))) short s16x8;

__device__ __forceinline__ uint16_t f2b(float f) {
  uint32_t u = __float_as_uint(f);
  u += 0x7fffu + ((u >> 16) & 1u);
  return (uint16_t)(u >> 16);
}
__device__ __forceinline__ float b2f(uint16_t h) {
  return __uint_as_float(((uint32_t)h) << 16);
}

#define GLOAD_LDS16(gp, lp)                                                    \
  __builtin_amdgcn_global_load_lds(                                            \
      (__attribute__((address_space(1))) void*)(gp),                           \
      (__attribute__((address_space(3))) void*)(lp), 16, 0, 0)

// ---------------- convert x -> bf16 ----------------
__global__ __launch_bounds__(256) void cvt_x_kernel(const float* __restrict__ x,
                                                    uint16_t* __restrict__ xb) {
  long i = ((long)blockIdx.x * 256 + threadIdx.x) * 4;
  f32x4 v = *(const f32x4*)(x + i);
  uint64_t p = (uint64_t)f2b(v[0]) | ((uint64_t)f2b(v[1]) << 16) |
               ((uint64_t)f2b(v[2]) << 32) | ((uint64_t)f2b(v[3]) << 48);
  *(uint64_t*)(xb + i) = p;
}

// ---------------- weights: transpose + bf16, build qkv bias ----------------
__global__ __launch_bounds__(256) void prep_weights(
    const float* __restrict__ qkv_w, const float* __restrict__ proj_w,
    const float* __restrict__ q_bias, const float* __restrict__ v_bias,
    uint16_t* __restrict__ qkv_wT, uint16_t* __restrict__ proj_wT,
    float* __restrict__ qkv_bias) {
  int i = blockIdx.x * 256 + threadIdx.x;
  if (i < QKVN * CDIM) {  // qkv_wT[n][k] = qkv_w[k][n]
    int nn = i / CDIM, kk = i % CDIM;
    qkv_wT[i] = f2b(qkv_w[(long)kk * QKVN + nn]);
  }
  if (i < CDIM * CDIM) {  // proj_wT[n][k] = proj_w[k][n]
    int nn = i / CDIM, kk = i % CDIM;
    proj_wT[i] = f2b(proj_w[(long)kk * CDIM + nn]);
  }
  if (i < QKVN) {
    float bv = (i < 512) ? q_bias[i] : (i < 1024 ? 0.f : v_bias[i - 1024]);
    qkv_bias[i] = bv;
  }
}

// ---------------- RPE bias table: 169 x 16, value = 16*sigmoid(mlp) --------
__global__ __launch_bounds__(256) void rpe_table(const float* __restrict__ w1,
                                                 const float* __restrict__ b1,
                                                 const float* __restrict__ w2,
                                                 float* __restrict__ bias16) {
  int i = blockIdx.x * 256 + threadIdx.x;
  if (i >= 169 * 16) return;
  int f = i >> 4, h = i & 15;
  float d0 = (float)((f % 13) - 6);  // feature 0 = ch[j]
  float d1 = (float)((f / 13) - 6);  // feature 1 = ch[i]
  const float inv_log8 = 0.4808983469629878f;  // 1/ln(8)
  float v0 = (d0 / 11.0f) * (8.0f / 11.0f);
  float v1 = (d1 / 11.0f) * (8.0f / 11.0f);
  float f0 = copysignf(log1pf(fabsf(v0)) * inv_log8, v0);
  if (v0 == 0.f) f0 = 0.f;
  float f1 = copysignf(log1pf(fabsf(v1)) * inv_log8, v1);
  if (v1 == 0.f) f1 = 0.f;
  float acc = 0.f;
  for (int k = 0; k < 512; ++k) {
    float h1 = fmaxf(f0 * w1[k] + f1 * w1[512 + k] + b1[k], 0.f);
    acc += h1 * w2[k * 16 + h];
  }
  bias16[i] = 16.f / (1.f + expf(-acc));
}

// ---------------- GEMM: C[M,N] = A[M,K] @ BT[N,K]^T + bias ----------------
// 128x128 tile, BK=64, 4 waves (2x2), mfma 16x16x32 bf16.
template <int EPI>  // 0: write bf16, 1: write f32
__global__ __launch_bounds__(256) void gemm_bt(const uint16_t* __restrict__ A,
                                               const uint16_t* __restrict__ BT,
                                               const float* __restrict__ bias,
                                               void* __restrict__ Cout,
                                               int N, int K, int ntn) {
  __shared__ uint16_t As[128 * 64];
  __shared__ uint16_t Bs[128 * 64];
  const int tid = threadIdx.x;
  const int wave = tid >> 6;
  const int lane = tid & 63;
  const int mt = blockIdx.x / ntn;
  const int nt = blockIdx.x % ntn;
  const long brow = (long)mt * 128;
  const int bcol = nt * 128;

  const int r_in = lane >> 3;          // row within 8-row chunk
  const int kkoff = (lane & 7) * 8;    // k offset within 64

  f32x4 acc[4][4];
#pragma unroll
  for (int i = 0; i < 4; ++i)
#pragma unroll
    for (int j = 0; j < 4; ++j) acc[i][j] = f32x4{0.f, 0.f, 0.f, 0.f};

  const int wr = wave >> 1, wc = wave & 1;

  for (int kt = 0; kt < K; kt += 64) {
    __syncthreads();
#pragma unroll
    for (int i = 0; i < 4; ++i) {
      const int c = wave * 4 + i;
      const int row = c * 8 + r_in;
      GLOAD_LDS16(A + (brow + row) * (long)K + kt + kkoff,
                  &As[c * 512 + lane * 8]);
      GLOAD_LDS16(BT + (long)(bcol + row) * K + kt + kkoff,
                  &Bs[c * 512 + lane * 8]);
    }
    __syncthreads();
#pragma unroll
    for (int kb = 0; kb < 2; ++kb) {
      s16x8 af[4], bf[4];
#pragma unroll
      for (int m = 0; m < 4; ++m) {
        const int row = wr * 64 + m * 16 + (lane & 15);
        af[m] = *(const s16x8*)&As[row * 64 + kb * 32 + (lane >> 4) * 8];
      }
#pragma unroll
      for (int n = 0; n < 4; ++n) {
        const int col = wc * 64 + n * 16 + (lane & 15);
        bf[n] = *(const s16x8*)&Bs[col * 64 + kb * 32 + (lane >> 4) * 8];
      }
#pragma unroll
      for (int m = 0; m < 4; ++m)
#pragma unroll
        for (int n = 0; n < 4; ++n)
          acc[m][n] = __builtin_amdgcn_mfma_f32_16x16x32_bf16(af[m], bf[n],
                                                              acc[m][n], 0, 0, 0);
    }
  }

#pragma unroll
  for (int m = 0; m < 4; ++m) {
    const int rbase = wr * 64 + m * 16 + ((lane >> 4) << 2);
#pragma unroll
    for (int n = 0; n < 4; ++n) {
      const int col = bcol + wc * 64 + n * 16 + (lane & 15);
      const float bv = bias[col];
#pragma unroll
      for (int r = 0; r < 4; ++r) {
        const long grow = brow + rbase + r;
        const float v = acc[m][n][r] + bv;
        if (EPI == 0)
          ((uint16_t*)Cout)[grow * N + col] = f2b(v);
        else
          ((float*)Cout)[grow * N + col] = v;
      }
    }
  }
}

// ---------------- normalize q,k rows (in-place, bf16) ----------------
__global__ __launch_bounds__(256) void norm_qk(uint16_t* __restrict__ qkv) {
  long g = (long)blockIdx.x * 8 + (threadIdx.x >> 5);
  int lane32 = threadIdx.x & 31;
  long row = g >> 5;
  int sub = (int)(g & 31);  // which*16 + h
  long off = row * QKVN + (long)(sub >> 4) * 512 + (sub & 15) * 32 + lane32;
  float v = b2f(qkv[off]);
  float ss = v * v;
#pragma unroll
  for (int o = 16; o; o >>= 1) ss += __shfl_xor(ss, o);
  v *= rsqrtf(fmaxf(ss, 1e-12f));
  qkv[off] = f2b(v);
}

// ---------------- attention per (window, head) ----------------
__global__ __launch_bounds__(256) void attn_kernel(
    const uint16_t* __restrict__ qkv, const float* __restrict__ mask,
    const float* __restrict__ logit_scale, const float* __restrict__ bias16,
    uint16_t* __restrict__ attn_out) {
  const int bb = blockIdx.x >> 4;
  const int h = blockIdx.x & 15;
  __shared__ float qs[49 * 32];
  __shared__ float kts[32 * 52];  // transposed k: [d][n]
  __shared__ float vs[49 * 32];
  __shared__ float S[49 * 52];
  const int tid = threadIdx.x;
  const long rowbase = (long)bb * NTOK;

  for (int idx = tid; idx < 49 * 32; idx += 256) {
    int n = idx >> 5, d = idx & 31;
    long ro = (rowbase + n) * QKVN;
    qs[idx] = b2f(qkv[ro + h * 32 + d]);
    kts[d * 52 + n] = b2f(qkv[ro + 512 + h * 32 + d]);
    vs[idx] = b2f(qkv[ro + 1024 + h * 32 + d]);
  }
  const float scale = __expf(fminf(logit_scale[h], 4.605170185988091f));
  __syncthreads();

  const float* mrow = mask + (long)(bb & 63) * 2401;
  for (int idx = tid; idx < 2401; idx += 256) {
    int a = idx / 49, b = idx - a * 49;
    float dot = 0.f;
#pragma unroll
    for (int d = 0; d < 32; ++d) dot += qs[a * 32 + d] * kts[d * 52 + b];
    int ridx = (a % 7 - b % 7 + 6) * 13 + (a / 7 - b / 7 + 6);
    S[a * 52 + b] = dot * scale + bias16[ridx * 16 + h] + mrow[idx];
  }
  __syncthreads();

  const int wave = tid >> 6, lane = tid & 63;
  for (int r = wave; r < 49; r += 4) {
    float v = (lane < 49) ? S[r * 52 + lane] : -1e30f;
    float m = v;
#pragma unroll
    for (int o = 32; o; o >>= 1) m = fmaxf(m, __shfl_xor(m, o));
    float e = (lane < 49) ? __expf(v - m) : 0.f;
    float s = e;
#pragma unroll
    for (int o = 32; o; o >>= 1) s += __shfl_xor(s, o);
    if (lane < 49) S[r * 52 + lane] = e / s;
  }
  __syncthreads();

  for (int idx = tid; idx < 49 * 32; idx += 256) {
    int a = idx >> 5, d = idx & 31;
    float o = 0.f;
#pragma unroll
    for (int m2 = 0; m2 < 49; ++m2) o += S[a * 52 + m2] * vs[m2 * 32 + d];
    attn_out[(rowbase + a) * CDIM + h * 32 + d] = f2b(o);
  }
}

extern "C" void kernel_launch(void* const* d_in, const int* in_sizes, int n_in,
                              void* d_out, int out_size, void* d_ws,
                              size_t ws_size, hipStream_t stream) {
  const float* x = (const float*)d_in[0];
  const float* mask = (const float*)d_in[1];
  const float* qkv_w = (const float*)d_in[2];
  const float* q_bias = (const float*)d_in[3];
  const float* v_bias = (const float*)d_in[4];
  const float* logit_scale = (const float*)d_in[5];
  const float* rpe_w1 = (const float*)d_in[6];
  const float* rpe_b1 = (const float*)d_in[7];
  const float* rpe_w2 = (const float*)d_in[8];
  const float* proj_w = (const float*)d_in[9];
  const float* proj_b = (const float*)d_in[10];

  char* ws = (char*)d_ws;
  uint16_t* qkvbuf = (uint16_t*)ws;                    // 100352*1536*2 = 308,281,344
  uint16_t* xb = (uint16_t*)(ws + 308281344L);         // 100352*512*2 = 102,760,448 (reused as attn_out)
  uint16_t* qkv_wT = (uint16_t*)(ws + 411041792L);     // 1536*512*2
  uint16_t* proj_wT = (uint16_t*)(ws + 412614656L);    // 512*512*2
  float* qkv_bias = (float*)(ws + 413138944L);         // 1536*4
  float* bias16 = (float*)(ws + 413145088L);           // 169*16*4

  cvt_x_kernel<<<(MROWS * CDIM) / 4 / 256, 256, 0, stream>>>(x, xb);
  prep_weights<<<(QKVN * CDIM) / 256, 256, 0, stream>>>(qkv_w, proj_w, q_bias,
                                                        v_bias, qkv_wT, proj_wT,
                                                        qkv_bias);
  rpe_table<<<11, 256, 0, stream>>>(rpe_w1, rpe_b1, rpe_w2, bias16);

  gemm_bt<0><<<784 * 12, 256, 0, stream>>>(xb, qkv_wT, qkv_bias, qkvbuf, QKVN,
                                           CDIM, 12);
  norm_qk<<<(MROWS * 32) / 8, 256, 0, stream>>>(qkvbuf);
  attn_kernel<<<BW * HEADS, 256, 0, stream>>>(qkvbuf, mask, logit_scale, bias16,
                                              xb);
  gemm_bt<1><<<784 * 4, 256, 0, stream>>>(xb, proj_wT, proj_b, d_out, CDIM,
                                          CDIM, 4);
}

// Round 2
// 953.988 us; speedup vs baseline: 1.4464x; 1.4464x over previous
//
#include <hip/hip_runtime.h>
#include <cstdint>

#define NTOK 49
#define CDIM 512
#define BW 2048
#define MROWS (BW * NTOK)   // 100352
#define QKVN 1536

typedef __attribute__((ext_vector_type(4))) float f32x4;
typedef __attribute__((ext_vector_type(8))) short s16x8;
typedef __attribute__((ext_vector_type(2))) unsigned int u32x2;

__device__ __forceinline__ uint16_t f2b(float f) {
  uint32_t u = __float_as_uint(f);
  u += 0x7fffu + ((u >> 16) & 1u);
  return (uint16_t)(u >> 16);
}
__device__ __forceinline__ float b2f(uint16_t h) {
  return __uint_as_float(((uint32_t)h) << 16);
}

#define GLOAD_LDS16(gp, lp)                                                    \
  __builtin_amdgcn_global_load_lds(                                            \
      (__attribute__((address_space(1))) void*)(gp),                           \
      (__attribute__((address_space(3))) void*)(lp), 16, 0, 0)

// ---------------- convert x -> bf16 ----------------
__global__ __launch_bounds__(256) void cvt_x_kernel(const float* __restrict__ x,
                                                    uint16_t* __restrict__ xb) {
  long i = ((long)blockIdx.x * 256 + threadIdx.x) * 4;
  f32x4 v = *(const f32x4*)(x + i);
  uint64_t p = (uint64_t)f2b(v[0]) | ((uint64_t)f2b(v[1]) << 16) |
               ((uint64_t)f2b(v[2]) << 32) | ((uint64_t)f2b(v[3]) << 48);
  *(uint64_t*)(xb + i) = p;
}

// ---------------- weights: transpose + bf16, build qkv bias ----------------
__global__ __launch_bounds__(256) void prep_weights(
    const float* __restrict__ qkv_w, const float* __restrict__ proj_w,
    const float* __restrict__ q_bias, const float* __restrict__ v_bias,
    uint16_t* __restrict__ qkv_wT, uint16_t* __restrict__ proj_wT,
    float* __restrict__ qkv_bias) {
  int i = blockIdx.x * 256 + threadIdx.x;
  if (i < QKVN * CDIM) {  // qkv_wT[n][k] = qkv_w[k][n]
    int nn = i / CDIM, kk = i % CDIM;
    qkv_wT[i] = f2b(qkv_w[(long)kk * QKVN + nn]);
  }
  if (i < CDIM * CDIM) {  // proj_wT[n][k] = proj_w[k][n]
    int nn = i / CDIM, kk = i % CDIM;
    proj_wT[i] = f2b(proj_w[(long)kk * CDIM + nn]);
  }
  if (i < QKVN) {
    float bv = (i < 512) ? q_bias[i] : (i < 1024 ? 0.f : v_bias[i - 1024]);
    qkv_bias[i] = bv;
  }
}

// ---------------- RPE bias table: 169 x 16, value = 16*sigmoid(mlp) --------
__global__ __launch_bounds__(256) void rpe_table(const float* __restrict__ w1,
                                                 const float* __restrict__ b1,
                                                 const float* __restrict__ w2,
                                                 float* __restrict__ bias16) {
  int i = blockIdx.x * 256 + threadIdx.x;
  if (i >= 169 * 16) return;
  int f = i >> 4, h = i & 15;
  float d0 = (float)((f % 13) - 6);
  float d1 = (float)((f / 13) - 6);
  const float inv_log8 = 0.4808983469629878f;  // 1/ln(8)
  float v0 = (d0 / 11.0f) * (8.0f / 11.0f);
  float v1 = (d1 / 11.0f) * (8.0f / 11.0f);
  float f0 = copysignf(log1pf(fabsf(v0)) * inv_log8, v0);
  if (v0 == 0.f) f0 = 0.f;
  float f1 = copysignf(log1pf(fabsf(v1)) * inv_log8, v1);
  if (v1 == 0.f) f1 = 0.f;
  float acc = 0.f;
  for (int k = 0; k < 512; ++k) {
    float h1 = fmaxf(f0 * w1[k] + f1 * w1[512 + k] + b1[k], 0.f);
    acc += h1 * w2[k * 16 + h];
  }
  bias16[i] = 16.f / (1.f + expf(-acc));
}

// ---------------- tiled extras in MFMA C-layout ----------------
// tile = mt*4+nt ; element (lane l, j): q = nt*16+(l&15), k = mt*16+(l>>4)*4+j
// mask_t[w][tile][l][j] : mask (+ -1e30 key padding)
// bias_t[h][tile][l][j] : 16*sigmoid(pb)
__global__ __launch_bounds__(256) void build_tiles(
    const float* __restrict__ mask, const float* __restrict__ bias16,
    float* __restrict__ mask_t, float* __restrict__ bias_t) {
  int bid = blockIdx.x;
  int l = threadIdx.x >> 2, j = threadIdx.x & 3;
  int gg = l >> 4, cc = l & 15;
  if (bid < 1024) {
    int w = bid >> 4, tile = bid & 15;
    int mt = tile >> 2, nt = tile & 3;
    int q = nt * 16 + cc, k = mt * 16 + gg * 4 + j;
    float v;
    if (k >= 49) v = -1e30f;
    else if (q >= 49) v = 0.f;
    else v = mask[(long)w * 2401 + q * 49 + k];
    mask_t[(long)bid * 256 + threadIdx.x] = v;
  } else {
    int idx = bid - 1024;
    int h = idx >> 4, tile = idx & 15;
    int mt = tile >> 2, nt = tile & 3;
    int q = nt * 16 + cc, k = mt * 16 + gg * 4 + j;
    float v = 0.f;
    if (q < 49 && k < 49) {
      int ridx = (q % 7 - k % 7 + 6) * 13 + (q / 7 - k / 7 + 6);
      v = bias16[ridx * 16 + h];
    }
    bias_t[(long)idx * 256 + threadIdx.x] = v;
  }
}

// ---------------- QKV GEMM with scatter epilogue ----------------
// writes q,k -> qk2[which][h][b][49][32], v -> vT[h][b][32][56]
__global__ __launch_bounds__(256) void gemm_qkv(
    const uint16_t* __restrict__ A, const uint16_t* __restrict__ BT,
    const float* __restrict__ bias, uint16_t* __restrict__ qk2,
    uint16_t* __restrict__ vTb) {
  __shared__ uint16_t As[128 * 64];
  __shared__ uint16_t Bs[128 * 64];
  const int tid = threadIdx.x;
  const int wave = tid >> 6;
  const int lane = tid & 63;
  const int bid = blockIdx.x;
  const int wg = (bid & 7) * 1176 + (bid >> 3);  // 9408/8 = 1176, XCD swizzle
  const int mt = wg / 12, nt = wg % 12;
  const long brow = (long)mt * 128;
  const int bcol = nt * 128;
  const int r_in = lane >> 3;
  const int kkoff = (lane & 7) * 8;

  f32x4 acc[4][4];
#pragma unroll
  for (int i = 0; i < 4; ++i)
#pragma unroll
    for (int j = 0; j < 4; ++j) acc[i][j] = f32x4{0.f, 0.f, 0.f, 0.f};
  const int wr = wave >> 1, wc = wave & 1;

  for (int kt = 0; kt < 512; kt += 64) {
    __syncthreads();
#pragma unroll
    for (int i = 0; i < 4; ++i) {
      const int c = wave * 4 + i;
      const int row = c * 8 + r_in;
      GLOAD_LDS16(A + (brow + row) * 512 + kt + kkoff, &As[c * 512 + lane * 8]);
      GLOAD_LDS16(BT + (long)(bcol + row) * 512 + kt + kkoff,
                  &Bs[c * 512 + lane * 8]);
    }
    __syncthreads();
#pragma unroll
    for (int kb = 0; kb < 2; ++kb) {
      s16x8 af[4], bf[4];
#pragma unroll
      for (int m = 0; m < 4; ++m) {
        const int row = wr * 64 + m * 16 + (lane & 15);
        af[m] = *(const s16x8*)&As[row * 64 + kb * 32 + (lane >> 4) * 8];
      }
#pragma unroll
      for (int n = 0; n < 4; ++n) {
        const int col = wc * 64 + n * 16 + (lane & 15);
        bf[n] = *(const s16x8*)&Bs[col * 64 + kb * 32 + (lane >> 4) * 8];
      }
#pragma unroll
      for (int m = 0; m < 4; ++m)
#pragma unroll
        for (int n = 0; n < 4; ++n)
          acc[m][n] = __builtin_amdgcn_mfma_f32_16x16x32_bf16(af[m], bf[n],
                                                              acc[m][n], 0, 0, 0);
    }
  }

  const int g = lane >> 4, cc = lane & 15;
#pragma unroll
  for (int n = 0; n < 4; ++n) {
    const int col = bcol + wc * 64 + n * 16 + cc;
    const int which = col >> 9;
    const int h = (col >> 5) & 15;
    const int d = col & 31;
    const float bv = bias[col];
#pragma unroll
    for (int m = 0; m < 4; ++m) {
#pragma unroll
      for (int r = 0; r < 4; ++r) {
        int grow = (int)brow + wr * 64 + m * 16 + g * 4 + r;
        int b = grow / 49, nn = grow - b * 49;
        uint16_t bh = f2b(acc[m][n][r] + bv);
        if (which == 2)
          vTb[((long)h * 2048 + b) * 1792 + d * 56 + nn] = bh;
        else
          qk2[((long)(which * 16 + h) * 2048 + b) * 1568 + nn * 32 + d] = bh;
      }
    }
  }
}

// ---------------- proj GEMM: C[M,N] = A[M,K] @ BT[N,K]^T + bias (f32 out) ---
template <int EPI>
__global__ __launch_bounds__(256) void gemm_bt(const uint16_t* __restrict__ A,
                                               const uint16_t* __restrict__ BT,
                                               const float* __restrict__ bias,
                                               void* __restrict__ Cout,
                                               int N, int K, int ntn) {
  __shared__ uint16_t As[128 * 64];
  __shared__ uint16_t Bs[128 * 64];
  const int tid = threadIdx.x;
  const int wave = tid >> 6;
  const int lane = tid & 63;
  const int nwg = gridDim.x;
  int bid = blockIdx.x;
  int wg = (bid & 7) * (nwg >> 3) + (bid >> 3);
  const int mt = wg / ntn;
  const int nt = wg % ntn;
  const long brow = (long)mt * 128;
  const int bcol = nt * 128;
  const int r_in = lane >> 3;
  const int kkoff = (lane & 7) * 8;

  f32x4 acc[4][4];
#pragma unroll
  for (int i = 0; i < 4; ++i)
#pragma unroll
    for (int j = 0; j < 4; ++j) acc[i][j] = f32x4{0.f, 0.f, 0.f, 0.f};
  const int wr = wave >> 1, wc = wave & 1;

  for (int kt = 0; kt < K; kt += 64) {
    __syncthreads();
#pragma unroll
    for (int i = 0; i < 4; ++i) {
      const int c = wave * 4 + i;
      const int row = c * 8 + r_in;
      GLOAD_LDS16(A + (brow + row) * (long)K + kt + kkoff,
                  &As[c * 512 + lane * 8]);
      GLOAD_LDS16(BT + (long)(bcol + row) * K + kt + kkoff,
                  &Bs[c * 512 + lane * 8]);
    }
    __syncthreads();
#pragma unroll
    for (int kb = 0; kb < 2; ++kb) {
      s16x8 af[4], bf[4];
#pragma unroll
      for (int m = 0; m < 4; ++m) {
        const int row = wr * 64 + m * 16 + (lane & 15);
        af[m] = *(const s16x8*)&As[row * 64 + kb * 32 + (lane >> 4) * 8];
      }
#pragma unroll
      for (int n = 0; n < 4; ++n) {
        const int col = wc * 64 + n * 16 + (lane & 15);
        bf[n] = *(const s16x8*)&Bs[col * 64 + kb * 32 + (lane >> 4) * 8];
      }
#pragma unroll
      for (int m = 0; m < 4; ++m)
#pragma unroll
        for (int n = 0; n < 4; ++n)
          acc[m][n] = __builtin_amdgcn_mfma_f32_16x16x32_bf16(af[m], bf[n],
                                                              acc[m][n], 0, 0, 0);
    }
  }

#pragma unroll
  for (int m = 0; m < 4; ++m) {
    const int rbase = wr * 64 + m * 16 + ((lane >> 4) << 2);
#pragma unroll
    for (int n = 0; n < 4; ++n) {
      const int col = bcol + wc * 64 + n * 16 + (lane & 15);
      const float bv = bias[col];
#pragma unroll
      for (int r = 0; r < 4; ++r) {
        const long grow = brow + rbase + r;
        const float v = acc[m][n][r] + bv;
        if (EPI == 0)
          ((uint16_t*)Cout)[grow * N + col] = f2b(v);
        else
          ((float*)Cout)[grow * N + col] = v;
      }
    }
  }
}

// ---------------- MFMA attention: one wave per (b,h) ----------------
__global__ __launch_bounds__(256) void attn_mfma(
    const uint16_t* __restrict__ qk2,   // [2][16][2048][49][32]
    const uint16_t* __restrict__ vTb,   // [16][2048][32][56]
    const float* __restrict__ logit_scale,
    const float* __restrict__ bias_t,   // [16][16][64][4]
    const float* __restrict__ mask_t,   // [64][16][64][4]
    uint16_t* __restrict__ outb) {      // [100352][512] bf16
  __shared__ uint16_t P[4][64 * 72];    // per-wave P, row stride 72 bf16 (144B)
  const int tid = threadIdx.x;
  const int wave = tid >> 6, lane = tid & 63;
  const int g = lane >> 4, c = lane & 15;
  const int b = blockIdx.x >> 2;
  const int h = ((blockIdx.x & 3) << 2) | wave;

  const long qbase = ((long)h * 2048 + b) * 1568;
  const long kbase = ((long)(16 + h) * 2048 + b) * 1568;

  // ---- load Q,K fragments direct from global; fuse l2-normalize ----
  s16x8 kf[4], qf[4];
#pragma unroll
  for (int t = 0; t < 4; ++t) {
    int row = t * 16 + c;
    s16x8 kv = {}, qv = {};
    if (row < 49) {
      kv = *(const s16x8*)(qk2 + kbase + row * 32 + g * 8);
      qv = *(const s16x8*)(qk2 + qbase + row * 32 + g * 8);
    }
    float kfv[8], qfv[8];
    float kss = 0.f, qss = 0.f;
#pragma unroll
    for (int m = 0; m < 8; ++m) {
      kfv[m] = b2f((uint16_t)kv[m]); kss += kfv[m] * kfv[m];
      qfv[m] = b2f((uint16_t)qv[m]); qss += qfv[m] * qfv[m];
    }
    kss += __shfl_xor(kss, 16); kss += __shfl_xor(kss, 32);
    qss += __shfl_xor(qss, 16); qss += __shfl_xor(qss, 32);
    float kr = rsqrtf(fmaxf(kss, 1e-12f));
    float qr = rsqrtf(fmaxf(qss, 1e-12f));
#pragma unroll
    for (int m = 0; m < 8; ++m) {
      kv[m] = (short)f2b(kfv[m] * kr);
      qv[m] = (short)f2b(qfv[m] * qr);
    }
    kf[t] = kv; qf[t] = qv;
  }

  // ---- S^T = K @ Q^T : s[mt][nt], row k = mt*16+g*4+j, col q = nt*16+c ----
  f32x4 s[4][4];
#pragma unroll
  for (int mt = 0; mt < 4; ++mt)
#pragma unroll
    for (int nt = 0; nt < 4; ++nt)
      s[mt][nt] = __builtin_amdgcn_mfma_f32_16x16x32_bf16(
          kf[mt], qf[nt], f32x4{0.f, 0.f, 0.f, 0.f}, 0, 0, 0);

  // ---- scale + bias + mask (tiled tables, C-layout) ----
  const float scale = __expf(fminf(logit_scale[h], 4.6051702f));
  const float* bt = bias_t + (long)h * 4096;
  const float* mk = mask_t + (long)(b & 63) * 4096;
#pragma unroll
  for (int mt = 0; mt < 4; ++mt)
#pragma unroll
    for (int nt = 0; nt < 4; ++nt) {
      int tile = mt * 4 + nt;
      f32x4 eb = *(const f32x4*)(bt + tile * 256 + lane * 4);
      f32x4 em = *(const f32x4*)(mk + tile * 256 + lane * 4);
#pragma unroll
      for (int j = 0; j < 4; ++j)
        s[mt][nt][j] = s[mt][nt][j] * scale + eb[j] + em[j];
    }

  // ---- softmax over k (= across mt, j in-lane, g cross-lane) per nt ----
#pragma unroll
  for (int nt = 0; nt < 4; ++nt) {
    float mx = -3.0e38f;
#pragma unroll
    for (int mt = 0; mt < 4; ++mt)
#pragma unroll
      for (int j = 0; j < 4; ++j) mx = fmaxf(mx, s[mt][nt][j]);
    mx = fmaxf(mx, __shfl_xor(mx, 16));
    mx = fmaxf(mx, __shfl_xor(mx, 32));
    float sum = 0.f;
#pragma unroll
    for (int mt = 0; mt < 4; ++mt)
#pragma unroll
      for (int j = 0; j < 4; ++j) {
        float e = __expf(s[mt][nt][j] - mx);
        s[mt][nt][j] = e; sum += e;
      }
    sum += __shfl_xor(sum, 16);
    sum += __shfl_xor(sum, 32);
    float inv = 1.0f / sum;
#pragma unroll
    for (int mt = 0; mt < 4; ++mt)
#pragma unroll
      for (int j = 0; j < 4; ++j) s[mt][nt][j] *= inv;
  }

  // ---- write P to LDS (bf16, XOR-swizzled rows of 144B) ----
  uint16_t* pw = P[wave];
#pragma unroll
  for (int mt = 0; mt < 4; ++mt)
#pragma unroll
    for (int nt = 0; nt < 4; ++nt) {
      unsigned lo = (unsigned)f2b(s[mt][nt][0]) | ((unsigned)f2b(s[mt][nt][1]) << 16);
      unsigned hi = (unsigned)f2b(s[mt][nt][2]) | ((unsigned)f2b(s[mt][nt][3]) << 16);
      int q = nt * 16 + c;
      int kb = (mt * 16 + g * 4) * 2;                    // byte offset in row
      int addr = q * 144 + (kb ^ ((q & 7) << 4));
      *(u32x2*)((char*)pw + addr) = u32x2{lo, hi};
    }
  __syncthreads();

  // ---- O = P @ V : A-frag from LDS P, B-frag (V^T) direct from global ----
  const uint16_t* vbase = vTb + ((long)h * 2048 + b) * 1792;
  f32x4 o[4][2];
#pragma unroll
  for (int qt = 0; qt < 4; ++qt)
#pragma unroll
    for (int dt = 0; dt < 2; ++dt) o[qt][dt] = f32x4{0.f, 0.f, 0.f, 0.f};

#pragma unroll
  for (int ks = 0; ks < 2; ++ks) {
    s16x8 vf[2];
#pragma unroll
    for (int dt = 0; dt < 2; ++dt) {
      int d = dt * 16 + c;
      int k0 = ks * 32 + g * 8;
      s16x8 vv = {};
      if (k0 < 49) vv = *(const s16x8*)(vbase + d * 56 + k0);
      vf[dt] = vv;
    }
#pragma unroll
    for (int qt = 0; qt < 4; ++qt) {
      int q = qt * 16 + c;
      int kbyte = (ks * 64 + g * 16) ^ ((q & 7) << 4);
      s16x8 pf = *(const s16x8*)((const char*)pw + q * 144 + kbyte);
#pragma unroll
      for (int dt = 0; dt < 2; ++dt)
        o[qt][dt] = __builtin_amdgcn_mfma_f32_16x16x32_bf16(pf, vf[dt],
                                                            o[qt][dt], 0, 0, 0);
    }
  }

  // ---- write O (bf16 rows for proj GEMM) ----
#pragma unroll
  for (int qt = 0; qt < 4; ++qt) {
    int q0 = qt * 16 + g * 4;
#pragma unroll
    for (int dt = 0; dt < 2; ++dt) {
      int d = dt * 16 + c;
#pragma unroll
      for (int j = 0; j < 4; ++j) {
        int q = q0 + j;
        if (q < 49)
          outb[((long)b * 49 + q) * 512 + h * 32 + d] = f2b(o[qt][dt][j]);
      }
    }
  }
}

extern "C" void kernel_launch(void* const* d_in, const int* in_sizes, int n_in,
                              void* d_out, int out_size, void* d_ws,
                              size_t ws_size, hipStream_t stream) {
  const float* x = (const float*)d_in[0];
  const float* mask = (const float*)d_in[1];
  const float* qkv_w = (const float*)d_in[2];
  const float* q_bias = (const float*)d_in[3];
  const float* v_bias = (const float*)d_in[4];
  const float* logit_scale = (const float*)d_in[5];
  const float* rpe_w1 = (const float*)d_in[6];
  const float* rpe_b1 = (const float*)d_in[7];
  const float* rpe_w2 = (const float*)d_in[8];
  const float* proj_w = (const float*)d_in[9];
  const float* proj_b = (const float*)d_in[10];

  char* ws = (char*)d_ws;
  uint16_t* xb       = (uint16_t*)ws;                   // 102,760,448 B (A for qkv GEMM; later attn out)
  uint16_t* qk2      = (uint16_t*)(ws + 102760448L);    // 205,520,896 B
  uint16_t* vTb      = (uint16_t*)(ws + 308281344L);    // 117,440,512 B
  uint16_t* qkv_wT   = (uint16_t*)(ws + 425721856L);    // 1,572,864 B
  uint16_t* proj_wT  = (uint16_t*)(ws + 427294720L);    //   524,288 B
  float*    qkv_bias = (float*)(ws + 427819008L);       //     6,144 B
  float*    bias16   = (float*)(ws + 427825152L);       //    10,816 B
  float*    bias_t   = (float*)(ws + 427835968L);       //   262,144 B
  float*    mask_t   = (float*)(ws + 428098112L);       // 1,048,576 B -> end 429,146,688

  cvt_x_kernel<<<50176, 256, 0, stream>>>(x, xb);
  prep_weights<<<3072, 256, 0, stream>>>(qkv_w, proj_w, q_bias, v_bias, qkv_wT,
                                         proj_wT, qkv_bias);
  rpe_table<<<11, 256, 0, stream>>>(rpe_w1, rpe_b1, rpe_w2, bias16);
  build_tiles<<<1280, 256, 0, stream>>>(mask, bias16, mask_t, bias_t);

  gemm_qkv<<<9408, 256, 0, stream>>>(xb, qkv_wT, qkv_bias, qk2, vTb);
  attn_mfma<<<8192, 256, 0, stream>>>(qk2, vTb, logit_scale, bias_t, mask_t, xb);
  gemm_bt<1><<<3136, 256, 0, stream>>>(xb, proj_wT, proj_b, d_out, 512, 512, 4);
}

// Round 3
// 676.448 us; speedup vs baseline: 2.0398x; 1.4103x over previous
//
#include <hip/hip_runtime.h>
#include <cstdint>

#define NTOK 49
#define CDIM 512
#define BW 2048
#define MROWS (BW * NTOK)   // 100352
#define QKVN 1536

typedef __attribute__((ext_vector_type(4))) float f32x4;
typedef __attribute__((ext_vector_type(8))) short s16x8;
typedef __attribute__((ext_vector_type(2))) unsigned int u32x2;

__device__ __forceinline__ uint16_t f2b(float f) {
  uint32_t u = __float_as_uint(f);
  u += 0x7fffu + ((u >> 16) & 1u);
  return (uint16_t)(u >> 16);
}
__device__ __forceinline__ float b2f(uint16_t h) {
  return __uint_as_float(((uint32_t)h) << 16);
}

#define GLOAD_LDS16(gp, lp)                                                    \
  __builtin_amdgcn_global_load_lds(                                            \
      (__attribute__((address_space(1))) void*)(gp),                           \
      (__attribute__((address_space(3))) void*)(lp), 16, 0, 0)

// ---------------- convert x -> bf16 ----------------
__global__ __launch_bounds__(256) void cvt_x_kernel(const float* __restrict__ x,
                                                    uint16_t* __restrict__ xb) {
  long i = ((long)blockIdx.x * 256 + threadIdx.x) * 4;
  f32x4 v = *(const f32x4*)(x + i);
  uint64_t p = (uint64_t)f2b(v[0]) | ((uint64_t)f2b(v[1]) << 16) |
               ((uint64_t)f2b(v[2]) << 32) | ((uint64_t)f2b(v[3]) << 48);
  *(uint64_t*)(xb + i) = p;
}

// ---------------- weights: transpose + bf16, build qkv bias ----------------
__global__ __launch_bounds__(256) void prep_weights(
    const float* __restrict__ qkv_w, const float* __restrict__ proj_w,
    const float* __restrict__ q_bias, const float* __restrict__ v_bias,
    uint16_t* __restrict__ qkv_wT, uint16_t* __restrict__ proj_wT,
    float* __restrict__ qkv_bias) {
  int i = blockIdx.x * 256 + threadIdx.x;
  if (i < QKVN * CDIM) {  // qkv_wT[n][k] = qkv_w[k][n]
    int nn = i / CDIM, kk = i % CDIM;
    qkv_wT[i] = f2b(qkv_w[(long)kk * QKVN + nn]);
  }
  if (i < CDIM * CDIM) {  // proj_wT[n][k] = proj_w[k][n]
    int nn = i / CDIM, kk = i % CDIM;
    proj_wT[i] = f2b(proj_w[(long)kk * CDIM + nn]);
  }
  if (i < QKVN) {
    float bv = (i < 512) ? q_bias[i] : (i < 1024 ? 0.f : v_bias[i - 1024]);
    qkv_bias[i] = bv;
  }
}

// ---------------- RPE bias table: 169 x 16, value = 16*sigmoid(mlp) --------
__global__ __launch_bounds__(256) void rpe_table(const float* __restrict__ w1,
                                                 const float* __restrict__ b1,
                                                 const float* __restrict__ w2,
                                                 float* __restrict__ bias16) {
  int i = blockIdx.x * 256 + threadIdx.x;
  if (i >= 169 * 16) return;
  int f = i >> 4, h = i & 15;
  float d0 = (float)((f % 13) - 6);
  float d1 = (float)((f / 13) - 6);
  const float inv_log8 = 0.4808983469629878f;  // 1/ln(8)
  float v0 = (d0 / 11.0f) * (8.0f / 11.0f);
  float v1 = (d1 / 11.0f) * (8.0f / 11.0f);
  float f0 = copysignf(log1pf(fabsf(v0)) * inv_log8, v0);
  if (v0 == 0.f) f0 = 0.f;
  float f1 = copysignf(log1pf(fabsf(v1)) * inv_log8, v1);
  if (v1 == 0.f) f1 = 0.f;
  float acc = 0.f;
  for (int k = 0; k < 512; ++k) {
    float h1 = fmaxf(f0 * w1[k] + f1 * w1[512 + k] + b1[k], 0.f);
    acc += h1 * w2[k * 16 + h];
  }
  bias16[i] = 16.f / (1.f + expf(-acc));
}

// ---------------- tiled extras in MFMA C-layout ----------------
// tile = mt*4+nt ; element (lane l, j): q = nt*16+(l&15), k = mt*16+(l>>4)*4+j
__global__ __launch_bounds__(256) void build_tiles(
    const float* __restrict__ mask, const float* __restrict__ bias16,
    float* __restrict__ mask_t, float* __restrict__ bias_t) {
  int bid = blockIdx.x;
  int l = threadIdx.x >> 2, j = threadIdx.x & 3;
  int gg = l >> 4, cc = l & 15;
  if (bid < 1024) {
    int w = bid >> 4, tile = bid & 15;
    int mt = tile >> 2, nt = tile & 3;
    int q = nt * 16 + cc, k = mt * 16 + gg * 4 + j;
    float v;
    if (k >= 49) v = -1e30f;
    else if (q >= 49) v = 0.f;
    else v = mask[(long)w * 2401 + q * 49 + k];
    mask_t[(long)bid * 256 + threadIdx.x] = v;
  } else {
    int idx = bid - 1024;
    int h = idx >> 4, tile = idx & 15;
    int mt = tile >> 2, nt = tile & 3;
    int q = nt * 16 + cc, k = mt * 16 + gg * 4 + j;
    float v = 0.f;
    if (q < 49 && k < 49) {
      int ridx = (q % 7 - k % 7 + 6) * 13 + (q / 7 - k / 7 + 6);
      v = bias16[ridx * 16 + h];
    }
    bias_t[(long)idx * 256 + threadIdx.x] = v;
  }
}

// ---------------- GEMM: C[M,N] = A[M,K] @ BT[N,K]^T + bias ----------------
// 128x128 tile, BK=64, 4 waves (2x2), mfma 16x16x32 bf16. XCD swizzle.
template <int EPI>  // 0: write bf16, 1: write f32
__global__ __launch_bounds__(256) void gemm_bt(const uint16_t* __restrict__ A,
                                               const uint16_t* __restrict__ BT,
                                               const float* __restrict__ bias,
                                               void* __restrict__ Cout,
                                               int N, int K, int ntn) {
  __shared__ uint16_t As[128 * 64];
  __shared__ uint16_t Bs[128 * 64];
  const int tid = threadIdx.x;
  const int wave = tid >> 6;
  const int lane = tid & 63;
  const int nwg = gridDim.x;
  int bid = blockIdx.x;
  int wg = (bid & 7) * (nwg >> 3) + (bid >> 3);
  const int mt = wg / ntn;
  const int nt = wg % ntn;
  const long brow = (long)mt * 128;
  const int bcol = nt * 128;
  const int r_in = lane >> 3;
  const int kkoff = (lane & 7) * 8;

  f32x4 acc[4][4];
#pragma unroll
  for (int i = 0; i < 4; ++i)
#pragma unroll
    for (int j = 0; j < 4; ++j) acc[i][j] = f32x4{0.f, 0.f, 0.f, 0.f};
  const int wr = wave >> 1, wc = wave & 1;

  for (int kt = 0; kt < K; kt += 64) {
    __syncthreads();
#pragma unroll
    for (int i = 0; i < 4; ++i) {
      const int c = wave * 4 + i;
      const int row = c * 8 + r_in;
      GLOAD_LDS16(A + (brow + row) * (long)K + kt + kkoff,
                  &As[c * 512 + lane * 8]);
      GLOAD_LDS16(BT + (long)(bcol + row) * K + kt + kkoff,
                  &Bs[c * 512 + lane * 8]);
    }
    __syncthreads();
#pragma unroll
    for (int kb = 0; kb < 2; ++kb) {
      s16x8 af[4], bf[4];
#pragma unroll
      for (int m = 0; m < 4; ++m) {
        const int row = wr * 64 + m * 16 + (lane & 15);
        af[m] = *(const s16x8*)&As[row * 64 + kb * 32 + (lane >> 4) * 8];
      }
#pragma unroll
      for (int n = 0; n < 4; ++n) {
        const int col = wc * 64 + n * 16 + (lane & 15);
        bf[n] = *(const s16x8*)&Bs[col * 64 + kb * 32 + (lane >> 4) * 8];
      }
#pragma unroll
      for (int m = 0; m < 4; ++m)
#pragma unroll
        for (int n = 0; n < 4; ++n)
          acc[m][n] = __builtin_amdgcn_mfma_f32_16x16x32_bf16(af[m], bf[n],
                                                              acc[m][n], 0, 0, 0);
    }
  }

#pragma unroll
  for (int m = 0; m < 4; ++m) {
    const int rbase = wr * 64 + m * 16 + ((lane >> 4) << 2);
#pragma unroll
    for (int n = 0; n < 4; ++n) {
      const int col = bcol + wc * 64 + n * 16 + (lane & 15);
      const float bv = bias[col];
#pragma unroll
      for (int r = 0; r < 4; ++r) {
        const long grow = brow + rbase + r;
        const float v = acc[m][n][r] + bv;
        if (EPI == 0)
          ((uint16_t*)Cout)[grow * N + col] = f2b(v);
        else
          ((float*)Cout)[grow * N + col] = v;
      }
    }
  }
}

// ---------------- MFMA attention: one wave per (b,h), row-major qkv -------
__global__ __launch_bounds__(256) void attn_mfma(
    const uint16_t* __restrict__ qkv,   // [100352][1536] bf16 (q|k|v)
    const float* __restrict__ logit_scale,
    const float* __restrict__ bias_t,   // [16][16][64][4]
    const float* __restrict__ mask_t,   // [64][16][64][4]
    uint16_t* __restrict__ outb) {      // [100352][512] bf16
  __shared__ uint16_t Vs[4][2048];      // per-wave V tile, linear [49][32]+pad
  __shared__ uint16_t P[4][64 * 72];    // per-wave P, row stride 72 bf16
  const int tid = threadIdx.x;
  const int wave = tid >> 6, lane = tid & 63;
  const int g = lane >> 4, c = lane & 15;
  const int b = blockIdx.x >> 2;
  const int h = ((blockIdx.x & 3) << 2) | wave;
  const long rbase = (long)b * 49;

  // ---- stage V tile (49x32) into LDS via linear global_load_lds ----
  uint16_t* vdst = Vs[wave];
#pragma unroll
  for (int i = 0; i < 4; ++i) {
    int chunk = i * 64 + lane;          // 0..255, need 0..195
    int row = chunk >> 2, part = chunk & 3;
    if (row > 48) { row = 0; part = 0; }  // clamp: pad gets harmless data
    GLOAD_LDS16(qkv + (rbase + row) * QKVN + 1024 + h * 32 + part * 8,
                vdst + i * 512 + lane * 8);
  }

  // ---- load Q,K fragments direct from global; fuse l2-normalize ----
  const long qoff = rbase * QKVN + h * 32;
  s16x8 kf[4], qf[4];
#pragma unroll
  for (int t = 0; t < 4; ++t) {
    int row = t * 16 + c;
    s16x8 kv = {}, qv = {};
    if (row < 49) {
      qv = *(const s16x8*)(qkv + qoff + (long)row * QKVN + g * 8);
      kv = *(const s16x8*)(qkv + qoff + (long)row * QKVN + 512 + g * 8);
    }
    float kfv[8], qfv[8];
    float kss = 0.f, qss = 0.f;
#pragma unroll
    for (int m = 0; m < 8; ++m) {
      kfv[m] = b2f((uint16_t)kv[m]); kss += kfv[m] * kfv[m];
      qfv[m] = b2f((uint16_t)qv[m]); qss += qfv[m] * qfv[m];
    }
    kss += __shfl_xor(kss, 16); kss += __shfl_xor(kss, 32);
    qss += __shfl_xor(qss, 16); qss += __shfl_xor(qss, 32);
    float kr = rsqrtf(fmaxf(kss, 1e-12f));
    float qr = rsqrtf(fmaxf(qss, 1e-12f));
#pragma unroll
    for (int m = 0; m < 8; ++m) {
      kv[m] = (short)f2b(kfv[m] * kr);
      qv[m] = (short)f2b(qfv[m] * qr);
    }
    kf[t] = kv; qf[t] = qv;
  }

  // ---- S^T = K @ Q^T : s[mt][nt], row k = mt*16+g*4+j, col q = nt*16+c ----
  f32x4 s[4][4];
#pragma unroll
  for (int mt = 0; mt < 4; ++mt)
#pragma unroll
    for (int nt = 0; nt < 4; ++nt)
      s[mt][nt] = __builtin_amdgcn_mfma_f32_16x16x32_bf16(
          kf[mt], qf[nt], f32x4{0.f, 0.f, 0.f, 0.f}, 0, 0, 0);

  // ---- scale + bias + mask (tiled tables, C-layout) ----
  const float scale = __expf(fminf(logit_scale[h], 4.6051702f));
  const float* bt = bias_t + (long)h * 4096;
  const float* mk = mask_t + (long)(b & 63) * 4096;
#pragma unroll
  for (int mt = 0; mt < 4; ++mt)
#pragma unroll
    for (int nt = 0; nt < 4; ++nt) {
      int tile = mt * 4 + nt;
      f32x4 eb = *(const f32x4*)(bt + tile * 256 + lane * 4);
      f32x4 em = *(const f32x4*)(mk + tile * 256 + lane * 4);
#pragma unroll
      for (int j = 0; j < 4; ++j)
        s[mt][nt][j] = s[mt][nt][j] * scale + eb[j] + em[j];
    }

  // ---- softmax over k (across mt, j in-lane, g cross-lane) per nt ----
#pragma unroll
  for (int nt = 0; nt < 4; ++nt) {
    float mx = -3.0e38f;
#pragma unroll
    for (int mt = 0; mt < 4; ++mt)
#pragma unroll
      for (int j = 0; j < 4; ++j) mx = fmaxf(mx, s[mt][nt][j]);
    mx = fmaxf(mx, __shfl_xor(mx, 16));
    mx = fmaxf(mx, __shfl_xor(mx, 32));
    float sum = 0.f;
#pragma unroll
    for (int mt = 0; mt < 4; ++mt)
#pragma unroll
      for (int j = 0; j < 4; ++j) {
        float e = __expf(s[mt][nt][j] - mx);
        s[mt][nt][j] = e; sum += e;
      }
    sum += __shfl_xor(sum, 16);
    sum += __shfl_xor(sum, 32);
    float inv = 1.0f / sum;
#pragma unroll
    for (int mt = 0; mt < 4; ++mt)
#pragma unroll
      for (int j = 0; j < 4; ++j) s[mt][nt][j] *= inv;
  }

  // ---- write P to LDS (bf16, XOR-swizzled rows of 144B) ----
  uint16_t* pw = P[wave];
#pragma unroll
  for (int mt = 0; mt < 4; ++mt)
#pragma unroll
    for (int nt = 0; nt < 4; ++nt) {
      unsigned lo = (unsigned)f2b(s[mt][nt][0]) | ((unsigned)f2b(s[mt][nt][1]) << 16);
      unsigned hi = (unsigned)f2b(s[mt][nt][2]) | ((unsigned)f2b(s[mt][nt][3]) << 16);
      int q = nt * 16 + c;
      int kb = (mt * 16 + g * 4) * 2;
      int addr = q * 144 + (kb ^ ((q & 7) << 4));
      *(u32x2*)((char*)pw + addr) = u32x2{lo, hi};
    }
  __syncthreads();   // covers V staging (vmcnt) + P writes (lgkmcnt)

  // ---- O = P @ V : A-frag from LDS P, B-frag from LDS V tile ----
  f32x4 o[4][2];
#pragma unroll
  for (int qt = 0; qt < 4; ++qt)
#pragma unroll
    for (int dt = 0; dt < 2; ++dt) o[qt][dt] = f32x4{0.f, 0.f, 0.f, 0.f};

#pragma unroll
  for (int ks = 0; ks < 2; ++ks) {
    s16x8 vf[2];
#pragma unroll
    for (int dt = 0; dt < 2; ++dt) {
      int d = dt * 16 + c;
      s16x8 vv;
#pragma unroll
      for (int jj = 0; jj < 8; ++jj) {
        int k = ks * 32 + g * 8 + jj;   // up to 63; pad rows hold finite junk,
        vv[jj] = (short)vdst[k * 32 + d];  // multiplied by P==0 there
      }
      vf[dt] = vv;
    }
#pragma unroll
    for (int qt = 0; qt < 4; ++qt) {
      int q = qt * 16 + c;
      int kbyte = (ks * 64 + g * 16) ^ ((q & 7) << 4);
      s16x8 pf = *(const s16x8*)((const char*)pw + q * 144 + kbyte);
#pragma unroll
      for (int dt = 0; dt < 2; ++dt)
        o[qt][dt] = __builtin_amdgcn_mfma_f32_16x16x32_bf16(pf, vf[dt],
                                                            o[qt][dt], 0, 0, 0);
    }
  }

  // ---- write O (bf16 rows for proj GEMM) ----
#pragma unroll
  for (int qt = 0; qt < 4; ++qt) {
    int q0 = qt * 16 + g * 4;
#pragma unroll
    for (int dt = 0; dt < 2; ++dt) {
      int d = dt * 16 + c;
#pragma unroll
      for (int j = 0; j < 4; ++j) {
        int q = q0 + j;
        if (q < 49)
          outb[(rbase + q) * 512 + h * 32 + d] = f2b(o[qt][dt][j]);
      }
    }
  }
}

extern "C" void kernel_launch(void* const* d_in, const int* in_sizes, int n_in,
                              void* d_out, int out_size, void* d_ws,
                              size_t ws_size, hipStream_t stream) {
  const float* x = (const float*)d_in[0];
  const float* mask = (const float*)d_in[1];
  const float* qkv_w = (const float*)d_in[2];
  const float* q_bias = (const float*)d_in[3];
  const float* v_bias = (const float*)d_in[4];
  const float* logit_scale = (const float*)d_in[5];
  const float* rpe_w1 = (const float*)d_in[6];
  const float* rpe_b1 = (const float*)d_in[7];
  const float* rpe_w2 = (const float*)d_in[8];
  const float* proj_w = (const float*)d_in[9];
  const float* proj_b = (const float*)d_in[10];

  char* ws = (char*)d_ws;
  uint16_t* xb       = (uint16_t*)ws;                   // 102,760,448 B (x bf16; later attn out)
  uint16_t* qkvbuf   = (uint16_t*)(ws + 102760448L);    // 308,281,344 B [100352][1536]
  uint16_t* qkv_wT   = (uint16_t*)(ws + 411041792L);    // 1,572,864 B
  uint16_t* proj_wT  = (uint16_t*)(ws + 412614656L);    //   524,288 B
  float*    qkv_bias = (float*)(ws + 413138944L);       //     6,144 B
  float*    bias16   = (float*)(ws + 413145088L);       //    10,816 B
  float*    bias_t   = (float*)(ws + 413155904L);       //   262,144 B
  float*    mask_t   = (float*)(ws + 413418048L);       // 1,048,576 B

  cvt_x_kernel<<<50176, 256, 0, stream>>>(x, xb);
  prep_weights<<<3072, 256, 0, stream>>>(qkv_w, proj_w, q_bias, v_bias, qkv_wT,
                                         proj_wT, qkv_bias);
  rpe_table<<<11, 256, 0, stream>>>(rpe_w1, rpe_b1, rpe_w2, bias16);
  build_tiles<<<1280, 256, 0, stream>>>(mask, bias16, mask_t, bias_t);

  gemm_bt<0><<<9408, 256, 0, stream>>>(xb, qkv_wT, qkv_bias, qkvbuf, QKVN, 512,
                                       12);
  attn_mfma<<<8192, 256, 0, stream>>>(qkvbuf, logit_scale, bias_t, mask_t, xb);
  gemm_bt<1><<<3136, 256, 0, stream>>>(xb, proj_wT, proj_b, d_out, 512, 512, 4);
}

// Round 4
// 547.227 us; speedup vs baseline: 2.5215x; 1.2361x over previous
//
#include <hip/hip_runtime.h>
#include <cstdint>

#define NTOK 49
#define CDIM 512
#define BW 2048
#define MROWS (BW * NTOK)   // 100352
#define QKVN 1536

typedef __attribute__((ext_vector_type(4))) float f32x4;
typedef __attribute__((ext_vector_type(8))) short s16x8;
typedef __attribute__((ext_vector_type(2))) unsigned int u32x2;

__device__ __forceinline__ uint16_t f2b(float f) {
  uint32_t u = __float_as_uint(f);
  u += 0x7fffu + ((u >> 16) & 1u);
  return (uint16_t)(u >> 16);
}
__device__ __forceinline__ float b2f(uint16_t h) {
  return __uint_as_float(((uint32_t)h) << 16);
}

#define GLOAD_LDS16(gp, lp)                                                    \
  __builtin_amdgcn_global_load_lds(                                            \
      (__attribute__((address_space(1))) void*)(gp),                           \
      (__attribute__((address_space(3))) void*)(lp), 16, 0, 0)

// ---------------- convert x -> bf16 ----------------
__global__ __launch_bounds__(256) void cvt_x_kernel(const float* __restrict__ x,
                                                    uint16_t* __restrict__ xb) {
  long i = ((long)blockIdx.x * 256 + threadIdx.x) * 4;
  f32x4 v = *(const f32x4*)(x + i);
  uint64_t p = (uint64_t)f2b(v[0]) | ((uint64_t)f2b(v[1]) << 16) |
               ((uint64_t)f2b(v[2]) << 32) | ((uint64_t)f2b(v[3]) << 48);
  *(uint64_t*)(xb + i) = p;
}

// ---------------- weights: transpose + bf16, build qkv bias ----------------
__global__ __launch_bounds__(256) void prep_weights(
    const float* __restrict__ qkv_w, const float* __restrict__ proj_w,
    const float* __restrict__ q_bias, const float* __restrict__ v_bias,
    uint16_t* __restrict__ qkv_wT, uint16_t* __restrict__ proj_wT,
    float* __restrict__ qkv_bias) {
  int i = blockIdx.x * 256 + threadIdx.x;
  if (i < QKVN * CDIM) {  // qkv_wT[n][k] = qkv_w[k][n]
    int nn = i / CDIM, kk = i % CDIM;
    qkv_wT[i] = f2b(qkv_w[(long)kk * QKVN + nn]);
  }
  if (i < CDIM * CDIM) {  // proj_wT[n][k] = proj_w[k][n]
    int nn = i / CDIM, kk = i % CDIM;
    proj_wT[i] = f2b(proj_w[(long)kk * CDIM + nn]);
  }
  if (i < QKVN) {
    float bv = (i < 512) ? q_bias[i] : (i < 1024 ? 0.f : v_bias[i - 1024]);
    qkv_bias[i] = bv;
  }
}

// ---------------- RPE bias table: 169 x 16, value = 16*sigmoid(mlp) --------
__global__ __launch_bounds__(256) void rpe_table(const float* __restrict__ w1,
                                                 const float* __restrict__ b1,
                                                 const float* __restrict__ w2,
                                                 float* __restrict__ bias16) {
  int i = blockIdx.x * 256 + threadIdx.x;
  if (i >= 169 * 16) return;
  int f = i >> 4, h = i & 15;
  float d0 = (float)((f % 13) - 6);
  float d1 = (float)((f / 13) - 6);
  const float inv_log8 = 0.4808983469629878f;  // 1/ln(8)
  float v0 = (d0 / 11.0f) * (8.0f / 11.0f);
  float v1 = (d1 / 11.0f) * (8.0f / 11.0f);
  float f0 = copysignf(log1pf(fabsf(v0)) * inv_log8, v0);
  if (v0 == 0.f) f0 = 0.f;
  float f1 = copysignf(log1pf(fabsf(v1)) * inv_log8, v1);
  if (v1 == 0.f) f1 = 0.f;
  float acc = 0.f;
  for (int k = 0; k < 512; ++k) {
    float h1 = fmaxf(f0 * w1[k] + f1 * w1[512 + k] + b1[k], 0.f);
    acc += h1 * w2[k * 16 + h];
  }
  bias16[i] = 16.f / (1.f + expf(-acc));
}

// ---------------- tiled extras in MFMA C-layout ----------------
__global__ __launch_bounds__(256) void build_tiles(
    const float* __restrict__ mask, const float* __restrict__ bias16,
    float* __restrict__ mask_t, float* __restrict__ bias_t) {
  int bid = blockIdx.x;
  int l = threadIdx.x >> 2, j = threadIdx.x & 3;
  int gg = l >> 4, cc = l & 15;
  if (bid < 1024) {
    int w = bid >> 4, tile = bid & 15;
    int mt = tile >> 2, nt = tile & 3;
    int q = nt * 16 + cc, k = mt * 16 + gg * 4 + j;
    float v;
    if (k >= 49) v = -1e30f;
    else if (q >= 49) v = 0.f;
    else v = mask[(long)w * 2401 + q * 49 + k];
    mask_t[(long)bid * 256 + threadIdx.x] = v;
  } else {
    int idx = bid - 1024;
    int h = idx >> 4, tile = idx & 15;
    int mt = tile >> 2, nt = tile & 3;
    int q = nt * 16 + cc, k = mt * 16 + gg * 4 + j;
    float v = 0.f;
    if (q < 49 && k < 49) {
      int ridx = (q % 7 - k % 7 + 6) * 13 + (q / 7 - k / 7 + 6);
      v = bias16[ridx * 16 + h];
    }
    bias_t[(long)idx * 256 + threadIdx.x] = v;
  }
}

// ============ 256x256 8-phase GEMM, K=512, BK=64, 8 waves (2Mx4N) ==========
// C[M,N] = A[M,512] @ BT[N,512]^T + bias. LDS 128KiB: 2buf x {A,B} x 2half.
// Swizzle: logical (r, colElem ce) -> phys r*64 + (ce ^ ((r&7)<<3)) per half.
// gload_lds writes linearly -> inverse-swizzled GLOBAL source (rule 21).

#define STAGE_A(tile, half, buf)                                               \
  {                                                                            \
    const uint16_t* s_ = srcA + (half) * (128L * 512) + (long)(tile) * 64;     \
    uint16_t* d_ = &lds[(buf) * 32768 + (half) * 8192 + tid * 8];              \
    GLOAD_LDS16(s_, d_);                                                       \
    GLOAD_LDS16(s_ + 64 * 512, d_ + 4096);                                     \
  }

#define STAGE_B(tile, half, buf)                                               \
  {                                                                            \
    const uint16_t* s_ = srcB + (half) * (128L * 512) + (long)(tile) * 64;     \
    uint16_t* d_ = &lds[(buf) * 32768 + 16384 + (half) * 8192 + tid * 8];      \
    GLOAD_LDS16(s_, d_);                                                       \
    GLOAD_LDS16(s_ + 64 * 512, d_ + 4096);                                     \
  }

#define VM4 asm volatile("s_waitcnt vmcnt(4)" ::: "memory");
#define VM0 asm volatile("s_waitcnt vmcnt(0)" ::: "memory");

#define PHASE(buf, q, STAGES, TAIL)                                            \
  {                                                                            \
    s16x8 a00 = *(const s16x8*)&lds[(buf)*32768 + arow + (2*(q))*1024 + ax0];  \
    s16x8 a01 = *(const s16x8*)&lds[(buf)*32768 + arow + (2*(q))*1024 + ax1];  \
    s16x8 a10 = *(const s16x8*)&lds[(buf)*32768 + arow + (2*(q)+1)*1024 + ax0];\
    s16x8 a11 = *(const s16x8*)&lds[(buf)*32768 + arow + (2*(q)+1)*1024 + ax1];\
    if ((q) == 0) {                                                            \
      _Pragma("unroll")                                                        \
      for (int nf = 0; nf < 4; ++nf) {                                         \
        bfr0[nf] = *(const s16x8*)&lds[(buf)*32768 + brow_ + nf*1024 + ax0];   \
        bfr1[nf] = *(const s16x8*)&lds[(buf)*32768 + brow_ + nf*1024 + ax1];   \
      }                                                                        \
    }                                                                          \
    STAGES                                                                     \
    __builtin_amdgcn_s_barrier();                                              \
    asm volatile("s_waitcnt lgkmcnt(0)" ::: "memory");                         \
    __builtin_amdgcn_sched_barrier(0);                                         \
    __builtin_amdgcn_s_setprio(1);                                             \
    _Pragma("unroll")                                                          \
    for (int nf = 0; nf < 4; ++nf) {                                           \
      acc[2*(q)][nf] = __builtin_amdgcn_mfma_f32_16x16x32_bf16(                \
          a00, bfr0[nf], acc[2*(q)][nf], 0, 0, 0);                             \
      acc[2*(q)][nf] = __builtin_amdgcn_mfma_f32_16x16x32_bf16(                \
          a01, bfr1[nf], acc[2*(q)][nf], 0, 0, 0);                             \
      acc[2*(q)+1][nf] = __builtin_amdgcn_mfma_f32_16x16x32_bf16(              \
          a10, bfr0[nf], acc[2*(q)+1][nf], 0, 0, 0);                           \
      acc[2*(q)+1][nf] = __builtin_amdgcn_mfma_f32_16x16x32_bf16(              \
          a11, bfr1[nf], acc[2*(q)+1][nf], 0, 0, 0);                           \
    }                                                                          \
    __builtin_amdgcn_s_setprio(0);                                             \
    TAIL                                                                       \
    __builtin_amdgcn_s_barrier();                                              \
  }

template <int EPI>  // 0: bf16 out, 1: f32 out
__global__ __launch_bounds__(512, 2) void gemm8p(const uint16_t* __restrict__ A,
                                                 const uint16_t* __restrict__ BT,
                                                 const float* __restrict__ bias,
                                                 void* __restrict__ Cout,
                                                 int N, int ntn) {
  __shared__ uint16_t lds[2 * 32768];  // 131072 B
  const int tid = threadIdx.x;
  const int wave = tid >> 6, lane = tid & 63;
  const int wm = wave >> 2, wn = wave & 3;  // 2 x 4 waves
  const int c = lane & 15, g = lane >> 4;

  const int bid = blockIdx.x;
  const int nwg = gridDim.x;
  const int wg = (bid & 7) * (nwg >> 3) + (bid >> 3);  // XCD swizzle (nwg%8==0)
  const int mt = wg / ntn, nt = wg % ntn;
  const long brow = (long)mt * 256;
  const int bcol = nt * 256;

  // staging source (inverse-swizzled global address)
  const int lr0 = tid >> 3;          // 0..63
  const int chunk = tid & 7;
  const int scol = (chunk ^ (lr0 & 7)) * 8;
  const uint16_t* srcA = A + (brow + lr0) * 512 + scol;
  const uint16_t* srcB = BT + ((long)bcol + lr0) * 512 + scol;

  // ds_read addresses (element offsets, swizzled)
  const int arow = wm * 8192 + c * 64;                       // + mf*1024
  const int brow_ = 16384 + (wn >> 1) * 8192 + ((wn & 1) * 64 + c) * 64;
  const int ax0 = (g * 8) ^ ((c & 7) * 8);
  const int ax1 = (32 + g * 8) ^ ((c & 7) * 8);

  f32x4 acc[8][4];
#pragma unroll
  for (int i = 0; i < 8; ++i)
#pragma unroll
    for (int j = 0; j < 4; ++j) acc[i][j] = f32x4{0.f, 0.f, 0.f, 0.f};
  s16x8 bfr0[4], bfr1[4];

  // prologue: A(0), B(0) -> buf0 ; B(1) -> buf1 ; first 4 halves must land
  STAGE_A(0, 0, 0); STAGE_A(0, 1, 0);
  STAGE_B(0, 0, 0); STAGE_B(0, 1, 0);
  STAGE_B(1, 0, 1); STAGE_B(1, 1, 1);
  asm volatile("s_waitcnt vmcnt(4)" ::: "memory");
  __builtin_amdgcn_s_barrier();

  // steady iterations: tiles 2i (buf0), 2i+1 (buf1); stage A(2i+1),B(2i+2),
  // A(2i+2),B(2i+3) per the half-tile free schedule.
  for (int i = 0; i < 3; ++i) {
    const int t0 = 2 * i;
    PHASE(0, 0, STAGE_A(t0 + 1, 0, 1), )
    PHASE(0, 1, STAGE_A(t0 + 1, 1, 1), )
    PHASE(0, 2, STAGE_B(t0 + 2, 0, 0), )
    PHASE(0, 3, STAGE_B(t0 + 2, 1, 0), VM4)
    PHASE(1, 0, STAGE_A(t0 + 2, 0, 0), )
    PHASE(1, 1, STAGE_A(t0 + 2, 1, 0), )
    PHASE(1, 2, STAGE_B(t0 + 3, 0, 1), )
    PHASE(1, 3, STAGE_B(t0 + 3, 1, 1), VM4)
  }
  // epilogue iteration: tiles 6 (buf0), 7 (buf1); only A(7) still to stage
  PHASE(0, 0, STAGE_A(7, 0, 1), )
  PHASE(0, 1, STAGE_A(7, 1, 1), )
  PHASE(0, 2, , )
  PHASE(0, 3, , VM0)
  PHASE(1, 0, , )
  PHASE(1, 1, , )
  PHASE(1, 2, , )
  PHASE(1, 3, , )

  // C write + bias
#pragma unroll
  for (int mf = 0; mf < 8; ++mf) {
#pragma unroll
    for (int nf = 0; nf < 4; ++nf) {
      const int col = bcol + wn * 64 + nf * 16 + c;
      const float bv = bias[col];
#pragma unroll
      for (int r = 0; r < 4; ++r) {
        const long grow = brow + wm * 128 + mf * 16 + g * 4 + r;
        const float v = acc[mf][nf][r] + bv;
        if (EPI == 0)
          ((uint16_t*)Cout)[grow * N + col] = f2b(v);
        else
          ((float*)Cout)[grow * N + col] = v;
      }
    }
  }
}

// ---------------- MFMA attention: one wave per (b,h), row-major qkv -------
__global__ __launch_bounds__(256) void attn_mfma(
    const uint16_t* __restrict__ qkv,   // [100352][1536] bf16 (q|k|v)
    const float* __restrict__ logit_scale,
    const float* __restrict__ bias_t,   // [16][16][64][4]
    const float* __restrict__ mask_t,   // [64][16][64][4]
    uint16_t* __restrict__ outb) {      // [100352][512] bf16
  __shared__ uint16_t Vs[4][2048];
  __shared__ uint16_t P[4][64 * 72];
  const int tid = threadIdx.x;
  const int wave = tid >> 6, lane = tid & 63;
  const int g = lane >> 4, c = lane & 15;
  const int b = blockIdx.x >> 2;
  const int h = ((blockIdx.x & 3) << 2) | wave;
  const long rbase = (long)b * 49;

  uint16_t* vdst = Vs[wave];
#pragma unroll
  for (int i = 0; i < 4; ++i) {
    int chunk = i * 64 + lane;
    int row = chunk >> 2, part = chunk & 3;
    if (row > 48) { row = 0; part = 0; }
    GLOAD_LDS16(qkv + (rbase + row) * QKVN + 1024 + h * 32 + part * 8,
                vdst + i * 512 + lane * 8);
  }

  const long qoff = rbase * QKVN + h * 32;
  s16x8 kf[4], qf[4];
#pragma unroll
  for (int t = 0; t < 4; ++t) {
    int row = t * 16 + c;
    s16x8 kv = {}, qv = {};
    if (row < 49) {
      qv = *(const s16x8*)(qkv + qoff + (long)row * QKVN + g * 8);
      kv = *(const s16x8*)(qkv + qoff + (long)row * QKVN + 512 + g * 8);
    }
    float kfv[8], qfv[8];
    float kss = 0.f, qss = 0.f;
#pragma unroll
    for (int m = 0; m < 8; ++m) {
      kfv[m] = b2f((uint16_t)kv[m]); kss += kfv[m] * kfv[m];
      qfv[m] = b2f((uint16_t)qv[m]); qss += qfv[m] * qfv[m];
    }
    kss += __shfl_xor(kss, 16); kss += __shfl_xor(kss, 32);
    qss += __shfl_xor(qss, 16); qss += __shfl_xor(qss, 32);
    float kr = rsqrtf(fmaxf(kss, 1e-12f));
    float qr = rsqrtf(fmaxf(qss, 1e-12f));
#pragma unroll
    for (int m = 0; m < 8; ++m) {
      kv[m] = (short)f2b(kfv[m] * kr);
      qv[m] = (short)f2b(qfv[m] * qr);
    }
    kf[t] = kv; qf[t] = qv;
  }

  f32x4 s[4][4];
#pragma unroll
  for (int mt = 0; mt < 4; ++mt)
#pragma unroll
    for (int nt = 0; nt < 4; ++nt)
      s[mt][nt] = __builtin_amdgcn_mfma_f32_16x16x32_bf16(
          kf[mt], qf[nt], f32x4{0.f, 0.f, 0.f, 0.f}, 0, 0, 0);

  const float scale = __expf(fminf(logit_scale[h], 4.6051702f));
  const float* bt = bias_t + (long)h * 4096;
  const float* mk = mask_t + (long)(b & 63) * 4096;
#pragma unroll
  for (int mt = 0; mt < 4; ++mt)
#pragma unroll
    for (int nt = 0; nt < 4; ++nt) {
      int tile = mt * 4 + nt;
      f32x4 eb = *(const f32x4*)(bt + tile * 256 + lane * 4);
      f32x4 em = *(const f32x4*)(mk + tile * 256 + lane * 4);
#pragma unroll
      for (int j = 0; j < 4; ++j)
        s[mt][nt][j] = s[mt][nt][j] * scale + eb[j] + em[j];
    }

#pragma unroll
  for (int nt = 0; nt < 4; ++nt) {
    float mx = -3.0e38f;
#pragma unroll
    for (int mt = 0; mt < 4; ++mt)
#pragma unroll
      for (int j = 0; j < 4; ++j) mx = fmaxf(mx, s[mt][nt][j]);
    mx = fmaxf(mx, __shfl_xor(mx, 16));
    mx = fmaxf(mx, __shfl_xor(mx, 32));
    float sum = 0.f;
#pragma unroll
    for (int mt = 0; mt < 4; ++mt)
#pragma unroll
      for (int j = 0; j < 4; ++j) {
        float e = __expf(s[mt][nt][j] - mx);
        s[mt][nt][j] = e; sum += e;
      }
    sum += __shfl_xor(sum, 16);
    sum += __shfl_xor(sum, 32);
    float inv = 1.0f / sum;
#pragma unroll
    for (int mt = 0; mt < 4; ++mt)
#pragma unroll
      for (int j = 0; j < 4; ++j) s[mt][nt][j] *= inv;
  }

  uint16_t* pw = P[wave];
#pragma unroll
  for (int mt = 0; mt < 4; ++mt)
#pragma unroll
    for (int nt = 0; nt < 4; ++nt) {
      unsigned lo = (unsigned)f2b(s[mt][nt][0]) | ((unsigned)f2b(s[mt][nt][1]) << 16);
      unsigned hi = (unsigned)f2b(s[mt][nt][2]) | ((unsigned)f2b(s[mt][nt][3]) << 16);
      int q = nt * 16 + c;
      int kb = (mt * 16 + g * 4) * 2;
      int addr = q * 144 + (kb ^ ((q & 7) << 4));
      *(u32x2*)((char*)pw + addr) = u32x2{lo, hi};
    }
  __syncthreads();

  f32x4 o[4][2];
#pragma unroll
  for (int qt = 0; qt < 4; ++qt)
#pragma unroll
    for (int dt = 0; dt < 2; ++dt) o[qt][dt] = f32x4{0.f, 0.f, 0.f, 0.f};

#pragma unroll
  for (int ks = 0; ks < 2; ++ks) {
    s16x8 vf[2];
#pragma unroll
    for (int dt = 0; dt < 2; ++dt) {
      int d = dt * 16 + c;
      s16x8 vv;
#pragma unroll
      for (int jj = 0; jj < 8; ++jj) {
        int k = ks * 32 + g * 8 + jj;
        vv[jj] = (short)vdst[k * 32 + d];
      }
      vf[dt] = vv;
    }
#pragma unroll
    for (int qt = 0; qt < 4; ++qt) {
      int q = qt * 16 + c;
      int kbyte = (ks * 64 + g * 16) ^ ((q & 7) << 4);
      s16x8 pf = *(const s16x8*)((const char*)pw + q * 144 + kbyte);
#pragma unroll
      for (int dt = 0; dt < 2; ++dt)
        o[qt][dt] = __builtin_amdgcn_mfma_f32_16x16x32_bf16(pf, vf[dt],
                                                            o[qt][dt], 0, 0, 0);
    }
  }

#pragma unroll
  for (int qt = 0; qt < 4; ++qt) {
    int q0 = qt * 16 + g * 4;
#pragma unroll
    for (int dt = 0; dt < 2; ++dt) {
      int d = dt * 16 + c;
#pragma unroll
      for (int j = 0; j < 4; ++j) {
        int q = q0 + j;
        if (q < 49)
          outb[(rbase + q) * 512 + h * 32 + d] = f2b(o[qt][dt][j]);
      }
    }
  }
}

extern "C" void kernel_launch(void* const* d_in, const int* in_sizes, int n_in,
                              void* d_out, int out_size, void* d_ws,
                              size_t ws_size, hipStream_t stream) {
  const float* x = (const float*)d_in[0];
  const float* mask = (const float*)d_in[1];
  const float* qkv_w = (const float*)d_in[2];
  const float* q_bias = (const float*)d_in[3];
  const float* v_bias = (const float*)d_in[4];
  const float* logit_scale = (const float*)d_in[5];
  const float* rpe_w1 = (const float*)d_in[6];
  const float* rpe_b1 = (const float*)d_in[7];
  const float* rpe_w2 = (const float*)d_in[8];
  const float* proj_w = (const float*)d_in[9];
  const float* proj_b = (const float*)d_in[10];

  char* ws = (char*)d_ws;
  uint16_t* xb       = (uint16_t*)ws;                   // x bf16; later attn out
  uint16_t* qkvbuf   = (uint16_t*)(ws + 102760448L);    // [100352][1536]
  uint16_t* qkv_wT   = (uint16_t*)(ws + 411041792L);
  uint16_t* proj_wT  = (uint16_t*)(ws + 412614656L);
  float*    qkv_bias = (float*)(ws + 413138944L);
  float*    bias16   = (float*)(ws + 413145088L);
  float*    bias_t   = (float*)(ws + 413155904L);
  float*    mask_t   = (float*)(ws + 413418048L);

  cvt_x_kernel<<<50176, 256, 0, stream>>>(x, xb);
  prep_weights<<<3072, 256, 0, stream>>>(qkv_w, proj_w, q_bias, v_bias, qkv_wT,
                                         proj_wT, qkv_bias);
  rpe_table<<<11, 256, 0, stream>>>(rpe_w1, rpe_b1, rpe_w2, bias16);
  build_tiles<<<1280, 256, 0, stream>>>(mask, bias16, mask_t, bias_t);

  gemm8p<0><<<2352, 512, 0, stream>>>(xb, qkv_wT, qkv_bias, qkvbuf, QKVN, 6);
  attn_mfma<<<8192, 256, 0, stream>>>(qkvbuf, logit_scale, bias_t, mask_t, xb);
  gemm8p<1><<<784, 512, 0, stream>>>(xb, proj_wT, proj_b, d_out, CDIM, 2);
}